// Round 6
// baseline (637.817 us; speedup 1.0000x reference)
//
#include <hip/hip_runtime.h>
#include <hip/hip_bf16.h>

#define B_ 128
#define T_ 300
#define TC_ 20
#define DW_ 16
#define DC_ 32
#define UC_ 32
#define UM_ 64
#define POS_ 20
#define PAR_ 8
#define VW_ 1834
#define VC_ 132
#define DIN_ 76
#define XS_ 80
#define NROW (B_*T_)

__device__ __forceinline__ float fast_sig(float x){
  return __builtin_amdgcn_rcpf(1.f + __expf(-x));
}
__device__ __forceinline__ float fast_tanh(float x){
  return __builtin_amdgcn_rcpf(1.f + __expf(-2.f*x))*2.f - 1.f;
}
__device__ __forceinline__ float bf2f(unsigned short s){
  unsigned int u = ((unsigned int)s) << 16;
  return __int_as_float(u);
}

// ---- prep: xzc[v][j] = emb_char[v]·char_Wx[:,j] + char_b[j]  (132 x 128)
__global__ void k_xzc(const float* __restrict__ emb_char, const float* __restrict__ Wx,
                      const float* __restrict__ bias, float* __restrict__ xzc){
  int v = blockIdx.x, j = threadIdx.x;
  float acc = bias[j];
  #pragma unroll
  for (int k=0;k<DC_;k++) acc += emb_char[v*DC_+k]*Wx[k*(4*UC_)+j];
  xzc[v*(4*UC_)+j] = acc;
}

// ---- prep: whT2[dir][u][g][k] = Wh_dir[k][g*64+u]   (2 x 64 x 4 x 64)
__global__ void k_whT(const float* __restrict__ Whf, const float* __restrict__ Whb,
                      float* __restrict__ o){
  int t = blockIdx.x*256 + threadIdx.x;     // 0..32767
  int dir = t >> 14;
  int u = (t >> 8) & 63;
  int g = (t >> 6) & 3;
  int k = t & 63;
  const float* W = dir ? Whb : Whf;
  o[t] = W[k*(4*UM_) + g*64 + u];
}

// ---- fill x cols [0..16) = word emb, [48..68) = pos, [68..76) = par
__global__ void k_xfill(const int* __restrict__ word_in, const float* __restrict__ emb_wor,
                        const float* __restrict__ pos, const float* __restrict__ par,
                        float* __restrict__ x){
  int r = blockIdx.x*4 + threadIdx.x/80;
  int c = threadIdx.x%80;
  float v;
  if (c < DW_)                     v = emb_wor[word_in[r]*DW_ + c];
  else if (c < DW_+UC_)            return;             // char kernel fills
  else if (c < DW_+UC_+POS_)       v = pos[r*POS_ + (c-(DW_+UC_))];
  else if (c < DIN_)               v = par[r*PAR_ + (c-(DW_+UC_+POS_))];
  else                             return;             // pad, never read
  x[r*XS_ + c] = v;
}

// ---- char LSTM: persistent blocks; thread = (seq, unit); 8 seqs x 32 units.
// Weights loaded+pinned ONCE per block, amortized over 10 seq-groups.
// h exchange within 32-lane group: same-wave LDS, no barrier in step loop.
__global__ __launch_bounds__(256,1) void k_char(const int* __restrict__ char_in,
        const float* __restrict__ xzc, const float* __restrict__ Wh,
        float* __restrict__ x){
  __shared__ float hbuf[8][32];
  __shared__ int sidx[8*TC_];
  const int tid = threadIdx.x;
  const int u = tid & 31;               // unit
  const int grp = tid >> 5;             // seq-in-group 0..7

  float wh[4][32];
  #pragma unroll
  for (int g=0; g<4; g++)
    #pragma unroll
    for (int k=0; k<32; k++)
      wh[g][k] = Wh[k*(4*UC_) + g*32 + u];
  #pragma unroll
  for (int g=0; g<4; g++)
    #pragma unroll
    for (int k=0; k<32; k++)
      asm volatile("" : "+v"(wh[g][k]));

  for (int it=0; it<10; it++){
    const int gb = blockIdx.x*10 + it;  // global group of 8 seqs
    const int seq = gb*8 + grp;
    __syncthreads();                    // WAR on sidx/hbuf from prev group
    if (tid < 8*TC_) sidx[tid] = char_in[gb*(8*TC_) + tid];
    hbuf[grp][u] = 0.f;
    __syncthreads();

    float h = 0.f, c = 0.f;
    int idx = sidx[grp*TC_ + 0];
    float zx[4];
    #pragma unroll
    for (int g=0; g<4; g++) zx[g] = xzc[idx*(4*UC_) + g*32 + u];

    for (int t=0; t<TC_; t++){
      int idxn = (t+1 < TC_) ? sidx[grp*TC_ + t+1] : 0;
      float nzx[4];
      #pragma unroll
      for (int g=0; g<4; g++) nzx[g] = xzc[idxn*(4*UC_) + g*32 + u]; // prefetch

      float zi = zx[0], zf = zx[1], zg = zx[2], zo = zx[3];
      const float4* hb4 = reinterpret_cast<const float4*>(&hbuf[grp][0]);
      #pragma unroll
      for (int k4=0; k4<8; k4++){
        float4 hv = hb4[k4];
        float he[4] = {hv.x, hv.y, hv.z, hv.w};
        #pragma unroll
        for (int e=0; e<4; e++){
          int k = k4*4+e;
          zi += he[e]*wh[0][k]; zf += he[e]*wh[1][k];
          zg += he[e]*wh[2][k]; zo += he[e]*wh[3][k];
        }
      }
      float cn = fast_sig(zf)*c + fast_sig(zi)*fast_tanh(zg);
      float hn = fast_sig(zo)*fast_tanh(cn);
      bool m = (idx != 0);
      c = m ? cn : c;
      h = m ? hn : h;
      hbuf[grp][u] = h;                 // same-wave exchange
      idx = idxn;
      #pragma unroll
      for (int g=0; g<4; g++) zx[g] = nzx[g];
    }
    x[seq*XS_ + DW_ + u] = h;
  }
}

// ---- xz GEMM: j<256 fwd, j>=256 bwd; output layout [row][dir][u][g] bf16
__global__ __launch_bounds__(512,1) void k_xz(const float* __restrict__ x,
      const float* __restrict__ Wx_f, const float* __restrict__ b_f,
      const float* __restrict__ Wx_b, const float* __restrict__ b_b,
      __hip_bfloat16* __restrict__ xz){
  __shared__ float xs[16*XS_];
  const int j = threadIdx.x;
  const int jj = j & 255;
  const bool bwd = (j >= 256);
  const float* Wx = bwd ? Wx_b : Wx_f;
  const float bj = bwd ? b_b[jj] : b_f[jj];
  const int u = jj & 63, g = jj >> 6;
  const int ocol = (bwd ? 256 : 0) + u*4 + g;

  float w[DIN_];
  #pragma unroll
  for (int k=0; k<DIN_; k++) w[k] = Wx[k*(4*UM_) + jj];
  #pragma unroll
  for (int k=0; k<DIN_; k++) asm volatile("" : "+v"(w[k]));

  const int rowbase = blockIdx.x*16;
  for (int i=j; i<16*XS_; i+=512) xs[i] = x[rowbase*XS_ + i];
  __syncthreads();

  for (int r=0; r<16; r++){
    const float4* xr = reinterpret_cast<const float4*>(&xs[r*XS_]);
    float a0=bj, a1=0.f, a2=0.f, a3=0.f;
    #pragma unroll
    for (int c4=0; c4<19; c4++){
      float4 v = xr[c4];
      a0 += v.x*w[4*c4+0]; a1 += v.y*w[4*c4+1];
      a2 += v.z*w[4*c4+2]; a3 += v.w*w[4*c4+3];
    }
    xz[(size_t)(rowbase+r)*512 + ocol] = __float2bfloat16((a0+a1)+(a2+a3));
  }
}

// ---- word LSTM: ONE WAVE per (batch,dir). Lane u owns unit u, all 4 gates.
// 256 scalar weights/lane pinned in VGPRs; h broadcast via same-wave LDS;
// ZERO barriers in the step loop.
__global__ __launch_bounds__(64,1) void k_rnn(const __hip_bfloat16* __restrict__ xz,
      const int* __restrict__ word_in, const float* __restrict__ whT2,
      float* __restrict__ hcat){
  __shared__ float hbuf[UM_];
  const int u = threadIdx.x;
  const int dir = blockIdx.x & 1;
  const int b = blockIdx.x >> 1;

  float wt[4][64];
  const float4* wp = reinterpret_cast<const float4*>(whT2 + (size_t)(dir*64+u)*256);
  #pragma unroll
  for (int g=0; g<4; g++)
    #pragma unroll
    for (int k4=0; k4<16; k4++){
      float4 v = wp[g*16 + k4];
      wt[g][k4*4+0]=v.x; wt[g][k4*4+1]=v.y; wt[g][k4*4+2]=v.z; wt[g][k4*4+3]=v.w;
    }
  #pragma unroll
  for (int g=0; g<4; g++)
    #pragma unroll
    for (int k=0; k<64; k++)
      asm volatile("" : "+v"(wt[g][k]));

  hbuf[u] = 0.f;
  float h = 0.f, cc = 0.f;

  int row = b*T_ + (dir ? T_-1 : 0);
  const int rstep = dir ? -1 : 1;
  const __hip_bfloat16* xp = xz + (size_t)row*512 + dir*256 + u*4;
  const ptrdiff_t dstep = dir ? -512 : 512;
  float* hout = hcat + (size_t)row*(2*UM_) + dir*UM_ + u;
  const ptrdiff_t hstep = dir ? -(2*UM_) : (2*UM_);

  ushort4 zxu = *reinterpret_cast<const ushort4*>(xp);
  int mw = word_in[row];

  for (int t=0; t<T_; t++){
    ushort4 zxn = {0,0,0,0}; int mwn = 0;
    if (t+1 < T_){
      zxn = *reinterpret_cast<const ushort4*>(xp + dstep);   // prefetch
      mwn = word_in[row + rstep];                            // uniform -> s_load
    }
    float zi = bf2f(zxu.x), zf = bf2f(zxu.y), zg = bf2f(zxu.z), zo = bf2f(zxu.w);
    const float4* hb4 = reinterpret_cast<const float4*>(hbuf);
    #pragma unroll
    for (int k4=0; k4<16; k4++){
      float4 hv = hb4[k4];
      float he[4] = {hv.x, hv.y, hv.z, hv.w};
      #pragma unroll
      for (int e=0; e<4; e++){
        int k = k4*4+e;
        zi += he[e]*wt[0][k]; zf += he[e]*wt[1][k];
        zg += he[e]*wt[2][k]; zo += he[e]*wt[3][k];
      }
    }
    float cn = fast_sig(zf)*cc + fast_sig(zi)*fast_tanh(zg);
    float hn = fast_sig(zo)*fast_tanh(cn);
    if (mw != 0){ cc = cn; h = hn; }
    hbuf[u] = h;                        // same-wave, in-order DS pipe
    *hout = h;                          // fire-and-forget
    hout += hstep;
    row += rstep; zxu = zxn; mw = mwn; xp += dstep;
  }
}

// ---- dense + softmax
__global__ void k_dense(const float* __restrict__ hcat, const float* __restrict__ W,
                        const float* __restrict__ bias, float* __restrict__ out){
  int r = blockIdx.x*256 + threadIdx.x;
  const float4* h4 = reinterpret_cast<const float4*>(hcat + (size_t)r*(2*UM_));
  float a0=bias[0], a1=bias[1], a2=bias[2], a3=bias[3];
  #pragma unroll
  for (int k4=0;k4<32;k4++){
    float4 hv = h4[k4];
    float he[4] = {hv.x, hv.y, hv.z, hv.w};
    #pragma unroll
    for (int e=0;e<4;e++){
      int k = k4*4+e;
      a0 += he[e]*W[k*4+0]; a1 += he[e]*W[k*4+1];
      a2 += he[e]*W[k*4+2]; a3 += he[e]*W[k*4+3];
    }
  }
  float mx = fmaxf(fmaxf(a0,a1), fmaxf(a2,a3));
  float e0=__expf(a0-mx), e1=__expf(a1-mx), e2=__expf(a2-mx), e3=__expf(a3-mx);
  float s = __builtin_amdgcn_rcpf(e0+e1+e2+e3);
  out[r*4+0]=e0*s; out[r*4+1]=e1*s; out[r*4+2]=e2*s; out[r*4+3]=e3*s;
}

extern "C" void kernel_launch(void* const* d_in, const int* in_sizes, int n_in,
                              void* d_out, int out_size, void* d_ws, size_t ws_size,
                              hipStream_t stream) {
  const int*   word_in  = (const int*)  d_in[0];
  const int*   char_in  = (const int*)  d_in[1];
  const float* inp_pos  = (const float*)d_in[2];
  const float* inp_par  = (const float*)d_in[3];
  const float* emb_wor  = (const float*)d_in[4];
  const float* emb_char = (const float*)d_in[5];
  const float* char_Wx  = (const float*)d_in[6];
  const float* char_Wh  = (const float*)d_in[7];
  const float* char_b   = (const float*)d_in[8];
  const float* fwd_Wx   = (const float*)d_in[9];
  const float* fwd_Wh   = (const float*)d_in[10];
  const float* fwd_b    = (const float*)d_in[11];
  const float* bwd_Wx   = (const float*)d_in[12];
  const float* bwd_Wh   = (const float*)d_in[13];
  const float* bwd_b    = (const float*)d_in[14];
  const float* dense_W  = (const float*)d_in[15];
  const float* dense_b  = (const float*)d_in[16];
  float* out = (float*)d_out;

  float* xw   = (float*)d_ws;                      // NROW*80  f32
  float* hcat = xw + (size_t)NROW*XS_;             // NROW*128 f32
  float* xzc  = hcat + (size_t)NROW*128;           // 132*128  f32
  float* whT2 = xzc + (size_t)VC_*128;             // 2*64*4*64 f32
  __hip_bfloat16* xzw = (__hip_bfloat16*)(whT2 + 2*64*4*64); // NROW*512 bf16

  k_xzc  <<<VC_, 4*UC_, 0, stream>>>(emb_char, char_Wx, char_b, xzc);
  k_whT  <<<128, 256, 0, stream>>>(fwd_Wh, bwd_Wh, whT2);
  k_xfill<<<NROW/4, 320, 0, stream>>>(word_in, emb_wor, inp_pos, inp_par, xw);
  k_char <<<480, 256, 0, stream>>>(char_in, xzc, char_Wh, xw);
  k_xz   <<<NROW/16, 512, 0, stream>>>(xw, fwd_Wx, fwd_b, bwd_Wx, bwd_b, xzw);
  k_rnn  <<<2*B_, 64, 0, stream>>>(xzw, word_in, whT2, hcat);
  k_dense<<<NROW/256, 256, 0, stream>>>(hcat, dense_W, dense_b, out);
}

// Round 7
// 412.019 us; speedup vs baseline: 1.5480x; 1.5480x over previous
//
#include <hip/hip_runtime.h>
#include <hip/hip_bf16.h>

#define B_ 128
#define T_ 300
#define TC_ 20
#define DW_ 16
#define DC_ 32
#define UC_ 32
#define UM_ 64
#define POS_ 20
#define PAR_ 8
#define VW_ 1834
#define VC_ 132
#define DIN_ 76
#define XS_ 80
#define NROW (B_*T_)

__device__ __forceinline__ float fast_sig(float x){
  return __builtin_amdgcn_rcpf(1.f + __expf(-x));
}
__device__ __forceinline__ float fast_tanh(float x){
  return __builtin_amdgcn_rcpf(1.f + __expf(-2.f*x))*2.f - 1.f;
}
__device__ __forceinline__ float bf2f(unsigned short s){
  unsigned int u = ((unsigned int)s) << 16;
  return __int_as_float(u);
}

// ---- prep: xzc[v][j] = emb_char[v]·char_Wx[:,j] + char_b[j]  (132 x 128)
__global__ void k_xzc(const float* __restrict__ emb_char, const float* __restrict__ Wx,
                      const float* __restrict__ bias, float* __restrict__ xzc){
  int v = blockIdx.x, j = threadIdx.x;
  float acc = bias[j];
  #pragma unroll
  for (int k=0;k<DC_;k++) acc += emb_char[v*DC_+k]*Wx[k*(4*UC_)+j];
  xzc[v*(4*UC_)+j] = acc;
}

// ---- fill x cols [0..16) = word emb, [48..68) = pos, [68..76) = par
__global__ void k_xfill(const int* __restrict__ word_in, const float* __restrict__ emb_wor,
                        const float* __restrict__ pos, const float* __restrict__ par,
                        float* __restrict__ x){
  int r = blockIdx.x*4 + threadIdx.x/80;
  int c = threadIdx.x%80;
  float v;
  if (c < DW_)                     v = emb_wor[word_in[r]*DW_ + c];
  else if (c < DW_+UC_)            return;             // char kernel fills
  else if (c < DW_+UC_+POS_)       v = pos[r*POS_ + (c-(DW_+UC_))];
  else if (c < DIN_)               v = par[r*PAR_ + (c-(DW_+UC_+POS_))];
  else                             return;             // pad, never read
  x[r*XS_ + c] = v;
}

// ---- char LSTM: wave = 1 seq; lane u&31 = unit, lane>>5 = gate-half.
// half0 computes gates i,f; half1 computes g,o. 64 weights/thread.
// All exchange is wave-local LDS (in-order DS pipe): ZERO barriers in step loop.
__global__ __launch_bounds__(512,2) void k_char(const int* __restrict__ char_in,
        const float* __restrict__ xzc, const float* __restrict__ Wh,
        float* __restrict__ x){
  __shared__ float hbuf[8][32];
  __shared__ float2 zex[8][64];
  __shared__ int sidx[8*TC_];
  const int tid = threadIdx.x;
  const int w = tid >> 6;               // wave = seq slot 0..7
  const int lane = tid & 63;
  const int u = lane & 31;
  const int half = lane >> 5;           // 0: i,f  1: g,o
  const int seq = blockIdx.x*8 + w;

  if (tid < 8*TC_) sidx[tid] = char_in[blockIdx.x*(8*TC_) + tid];
  if (half == 0) hbuf[w][u] = 0.f;

  // two gate-columns per thread: cols half*64+u (a) and half*64+32+u (b)
  float wa[32], wb[32];
  #pragma unroll
  for (int k=0;k<32;k++){
    wa[k] = Wh[k*(4*UC_) + half*64 + u];
    wb[k] = Wh[k*(4*UC_) + half*64 + 32 + u];
  }
  #pragma unroll
  for (int k=0;k<32;k++){
    asm volatile("" : "+v"(wa[k]));
    asm volatile("" : "+v"(wb[k]));
  }
  __syncthreads();

  float h = 0.f, c = 0.f;
  int idx = sidx[w*TC_ + 0];
  float za0 = xzc[idx*(4*UC_) + half*64 + u];
  float zb0 = xzc[idx*(4*UC_) + half*64 + 32 + u];

  for (int t=0; t<TC_; t++){
    int idxn = (t+1 < TC_) ? sidx[w*TC_ + t+1] : 0;
    float zan = xzc[idxn*(4*UC_) + half*64 + u];        // prefetch
    float zbn = xzc[idxn*(4*UC_) + half*64 + 32 + u];

    float za = za0, zb = zb0;
    const float4* hb = reinterpret_cast<const float4*>(&hbuf[w][0]);
    #pragma unroll
    for (int k4=0; k4<8; k4++){
      float4 hv = hb[k4];
      float he[4] = {hv.x, hv.y, hv.z, hv.w};
      #pragma unroll
      for (int e=0; e<4; e++){
        int k = k4*4+e;
        za += he[e]*wa[k];
        zb += he[e]*wb[k];
      }
    }
    zex[w][lane] = make_float2(za, zb);   // half1 publishes (zg,zo)
    if (half == 0){
      float2 p = zex[w][32+u];            // partner's g,o (same wave, in-order)
      float zi = za, zf = zb, zg = p.x, zo = p.y;
      float cn = fast_sig(zf)*c + fast_sig(zi)*fast_tanh(zg);
      float hn = fast_sig(zo)*fast_tanh(cn);
      bool m = (idx != 0);
      c = m ? cn : c;
      h = m ? hn : h;
      hbuf[w][u] = h;                     // visible to whole wave next step
    }
    idx = idxn; za0 = zan; zb0 = zbn;
  }
  if (half == 0) x[seq*XS_ + DW_ + u] = h;
}

// ---- xz GEMM: j<256 fwd, j>=256 bwd; output layout [row][dir][u*4+g] bf16
__global__ __launch_bounds__(512,1) void k_xz(const float* __restrict__ x,
      const float* __restrict__ Wx_f, const float* __restrict__ b_f,
      const float* __restrict__ Wx_b, const float* __restrict__ b_b,
      __hip_bfloat16* __restrict__ xz){
  __shared__ float xs[16*XS_];
  const int j = threadIdx.x;
  const int jj = j & 255;
  const bool bwd = (j >= 256);
  const float* Wx = bwd ? Wx_b : Wx_f;
  const float bj = bwd ? b_b[jj] : b_f[jj];
  const int u = jj & 63, g = jj >> 6;
  const int ocol = (bwd ? 256 : 0) + u*4 + g;

  float w[DIN_];
  #pragma unroll
  for (int k=0; k<DIN_; k++) w[k] = Wx[k*(4*UM_) + jj];
  #pragma unroll
  for (int k=0; k<DIN_; k++) asm volatile("" : "+v"(w[k]));

  const int rowbase = blockIdx.x*16;
  for (int i=j; i<16*XS_; i+=512) xs[i] = x[rowbase*XS_ + i];
  __syncthreads();

  for (int r=0; r<16; r++){
    const float4* xr = reinterpret_cast<const float4*>(&xs[r*XS_]);
    float a0=bj, a1=0.f, a2=0.f, a3=0.f;
    #pragma unroll
    for (int c4=0; c4<19; c4++){
      float4 v = xr[c4];
      a0 += v.x*w[4*c4+0]; a1 += v.y*w[4*c4+1];
      a2 += v.z*w[4*c4+2]; a3 += v.w*w[4*c4+3];
    }
    xz[(size_t)(rowbase+r)*512 + ocol] = __float2bfloat16((a0+a1)+(a2+a3));
  }
}

// ---- word LSTM: block = (batch,dir), 4 waves. Thread (w,l) computes the
// 4 gate-columns {m*64+l} over k-slice [w*16,w*16+16): 64 weights/thread.
// One raw barrier/step (lgkmcnt only); zpart double-buffered; per-wave hbuf.
__global__ __launch_bounds__(256,1) void k_rnn(const __hip_bfloat16* __restrict__ xz,
      const int* __restrict__ word_in,
      const float* __restrict__ Wh_f, const float* __restrict__ Wh_b,
      float* __restrict__ hcat){
  __shared__ float zpart[2][4][4*UM_];    // [buf][wave][col]
  __shared__ float hbuf[4][UM_];          // per-wave h copy
  __shared__ int wm[T_];
  const int j = threadIdx.x;
  const int w = j >> 6;
  const int l = j & 63;
  const int k0 = w*16;
  const int dir = blockIdx.x & 1;
  const int b = blockIdx.x >> 1;
  const float* Wh = dir ? Wh_b : Wh_f;

  float wh[4][16];
  #pragma unroll
  for (int m=0;m<4;m++)
    #pragma unroll
    for (int k=0;k<16;k++)
      wh[m][k] = Wh[(k0+k)*(4*UM_) + m*64 + l];
  #pragma unroll
  for (int m=0;m<4;m++)
    #pragma unroll
    for (int k=0;k<16;k++)
      asm volatile("" : "+v"(wh[m][k]));

  for (int t=j; t<T_; t+=256) wm[t] = word_in[b*T_ + (dir ? (T_-1-t) : t)];
  hbuf[w][l] = 0.f;
  __syncthreads();

  float h = 0.f, cc = 0.f;
  int row0 = b*T_ + (dir ? T_-1 : 0);
  const __hip_bfloat16* xp = xz + (size_t)row0*512 + dir*256 + l*4;
  const ptrdiff_t dstep = dir ? -512 : 512;
  float* hout = hcat + (size_t)row0*(2*UM_) + dir*UM_ + l;
  const ptrdiff_t hstep = dir ? -(2*UM_) : (2*UM_);

  ushort4 zxu = *reinterpret_cast<const ushort4*>(xp);

  for (int t=0; t<T_; t++){
    ushort4 zxn = {0,0,0,0};
    if (t+1 < T_) zxn = *reinterpret_cast<const ushort4*>(xp + dstep); // prefetch

    // partial dot over my k-slice for my 4 gate-columns
    const float4* hb = reinterpret_cast<const float4*>(&hbuf[w][k0]);
    float4 h0 = hb[0], h1 = hb[1], h2 = hb[2], h3 = hb[3];
    #pragma unroll
    for (int m=0;m<4;m++){
      float a0 = h0.x*wh[m][0]  + h0.y*wh[m][1]  + h0.z*wh[m][2]  + h0.w*wh[m][3];
      float a1 = h1.x*wh[m][4]  + h1.y*wh[m][5]  + h1.z*wh[m][6]  + h1.w*wh[m][7];
      float a2 = h2.x*wh[m][8]  + h2.y*wh[m][9]  + h2.z*wh[m][10] + h2.w*wh[m][11];
      float a3 = h3.x*wh[m][12] + h3.y*wh[m][13] + h3.z*wh[m][14] + h3.w*wh[m][15];
      zpart[t&1][w][m*64+l] = (a0+a1)+(a2+a3);
    }
    asm volatile("s_waitcnt lgkmcnt(0)" ::: "memory");
    __builtin_amdgcn_s_barrier();
    asm volatile("" ::: "memory");

    float zi = bf2f(zxu.x), zf = bf2f(zxu.y), zg = bf2f(zxu.z), zo = bf2f(zxu.w);
    #pragma unroll
    for (int w2=0; w2<4; w2++){
      zi += zpart[t&1][w2][      l];
      zf += zpart[t&1][w2][ 64 + l];
      zg += zpart[t&1][w2][128 + l];
      zo += zpart[t&1][w2][192 + l];
    }
    int mw = wm[t];
    float cn = fast_sig(zf)*cc + fast_sig(zi)*fast_tanh(zg);
    float hn = fast_sig(zo)*fast_tanh(cn);
    if (mw != 0){ cc = cn; h = hn; }      // all waves update redundantly
    hbuf[w][l] = h;                       // own-wave copy, in-order DS
    if (w == 0) *hout = h;                // fire-and-forget store
    hout += hstep;
    zxu = zxn; xp += dstep;
  }
}

// ---- dense + softmax
__global__ void k_dense(const float* __restrict__ hcat, const float* __restrict__ W,
                        const float* __restrict__ bias, float* __restrict__ out){
  int r = blockIdx.x*256 + threadIdx.x;
  const float4* h4 = reinterpret_cast<const float4*>(hcat + (size_t)r*(2*UM_));
  float a0=bias[0], a1=bias[1], a2=bias[2], a3=bias[3];
  #pragma unroll
  for (int k4=0;k4<32;k4++){
    float4 hv = h4[k4];
    float he[4] = {hv.x, hv.y, hv.z, hv.w};
    #pragma unroll
    for (int e=0;e<4;e++){
      int k = k4*4+e;
      a0 += he[e]*W[k*4+0]; a1 += he[e]*W[k*4+1];
      a2 += he[e]*W[k*4+2]; a3 += he[e]*W[k*4+3];
    }
  }
  float mx = fmaxf(fmaxf(a0,a1), fmaxf(a2,a3));
  float e0=__expf(a0-mx), e1=__expf(a1-mx), e2=__expf(a2-mx), e3=__expf(a3-mx);
  float s = __builtin_amdgcn_rcpf(e0+e1+e2+e3);
  out[r*4+0]=e0*s; out[r*4+1]=e1*s; out[r*4+2]=e2*s; out[r*4+3]=e3*s;
}

extern "C" void kernel_launch(void* const* d_in, const int* in_sizes, int n_in,
                              void* d_out, int out_size, void* d_ws, size_t ws_size,
                              hipStream_t stream) {
  const int*   word_in  = (const int*)  d_in[0];
  const int*   char_in  = (const int*)  d_in[1];
  const float* inp_pos  = (const float*)d_in[2];
  const float* inp_par  = (const float*)d_in[3];
  const float* emb_wor  = (const float*)d_in[4];
  const float* emb_char = (const float*)d_in[5];
  const float* char_Wx  = (const float*)d_in[6];
  const float* char_Wh  = (const float*)d_in[7];
  const float* char_b   = (const float*)d_in[8];
  const float* fwd_Wx   = (const float*)d_in[9];
  const float* fwd_Wh   = (const float*)d_in[10];
  const float* fwd_b    = (const float*)d_in[11];
  const float* bwd_Wx   = (const float*)d_in[12];
  const float* bwd_Wh   = (const float*)d_in[13];
  const float* bwd_b    = (const float*)d_in[14];
  const float* dense_W  = (const float*)d_in[15];
  const float* dense_b  = (const float*)d_in[16];
  float* out = (float*)d_out;

  float* xw   = (float*)d_ws;                      // NROW*80  f32
  float* hcat = xw + (size_t)NROW*XS_;             // NROW*128 f32
  float* xzc  = hcat + (size_t)NROW*128;           // 132*128  f32
  __hip_bfloat16* xzw = (__hip_bfloat16*)(xzc + (size_t)VC_*128); // NROW*512 bf16

  k_xzc  <<<VC_, 4*UC_, 0, stream>>>(emb_char, char_Wx, char_b, xzc);
  k_xfill<<<NROW/4, 320, 0, stream>>>(word_in, emb_wor, inp_pos, inp_par, xw);
  k_char <<<NROW/8, 512, 0, stream>>>(char_in, xzc, char_Wh, xw);
  k_xz   <<<NROW/16, 512, 0, stream>>>(xw, fwd_Wx, fwd_b, bwd_Wx, bwd_b, xzw);
  k_rnn  <<<2*B_, 256, 0, stream>>>(xzw, word_in, fwd_Wh, bwd_Wh, hcat);
  k_dense<<<NROW/256, 256, 0, stream>>>(hcat, dense_W, dense_b, out);
}

// Round 8
// 320.862 us; speedup vs baseline: 1.9878x; 1.2841x over previous
//
#include <hip/hip_runtime.h>
#include <hip/hip_bf16.h>

#define B_ 128
#define T_ 300
#define TC_ 20
#define DW_ 16
#define DC_ 32
#define UC_ 32
#define UM_ 64
#define POS_ 20
#define PAR_ 8
#define VW_ 1834
#define VC_ 132
#define DIN_ 76
#define XS_ 80
#define NROW (B_*T_)

typedef _Float16 half_t;
typedef half_t h2 __attribute__((ext_vector_type(2)));

__device__ __forceinline__ float fast_sig(float x){
  return __builtin_amdgcn_rcpf(1.f + __expf(-x));
}
__device__ __forceinline__ float fast_tanh(float x){
  return __builtin_amdgcn_rcpf(1.f + __expf(-2.f*x))*2.f - 1.f;
}
__device__ __forceinline__ float dot2u(unsigned int a, unsigned int b, float acc){
  union{unsigned int u; h2 h;} x, y; x.u = a; y.u = b;
#if __has_builtin(__builtin_amdgcn_fdot2)
  return __builtin_amdgcn_fdot2(x.h, y.h, acc, false);
#else
  return acc + (float)x.h.x*(float)y.h.x + (float)x.h.y*(float)y.h.y;
#endif
}
__device__ __forceinline__ float us2f(unsigned short s){
  union{unsigned short s; half_t h;} x; x.s = s; return (float)x.h;
}

// ---- prep: xzc[v][j] = emb_char[v]·char_Wx[:,j] + char_b[j]  (132 x 128) f32
__global__ void k_xzc(const float* __restrict__ emb_char, const float* __restrict__ Wx,
                      const float* __restrict__ bias, float* __restrict__ xzc){
  int v = blockIdx.x, j = threadIdx.x;
  float acc = bias[j];
  #pragma unroll
  for (int k=0;k<DC_;k++) acc += emb_char[v*DC_+k]*Wx[k*(4*UC_)+j];
  xzc[v*(4*UC_)+j] = acc;
}

// ---- prep: chT[j][k] = char_Wh[k][j] as f16  (128 x 32)
__global__ void k_chT(const float* __restrict__ Wh, half_t* __restrict__ o){
  int t = blockIdx.x*256 + threadIdx.x;   // 4096
  int j = t >> 5, k = t & 31;
  o[t] = (half_t)Wh[k*(4*UC_)+j];
}

// ---- prep: whT_h[dir][j][k] = Wh_dir[k][j] as f16  (2 x 256 x 64)
__global__ void k_whT(const float* __restrict__ Whf, const float* __restrict__ Whb,
                      half_t* __restrict__ o){
  int t = blockIdx.x*256 + threadIdx.x;   // 32768
  int dir = t >> 14;
  int j = (t >> 6) & 255;
  int k = t & 63;
  const float* W = dir ? Whb : Whf;
  o[t] = (half_t)W[k*(4*UM_)+j];
}

// ---- prep: wxT_h[dir][jj][k] = Wx_dir[k][jj] f16, k padded 76->96
__global__ void k_wxT(const float* __restrict__ Wxf, const float* __restrict__ Wxb,
                      half_t* __restrict__ o){
  int t = blockIdx.x*256 + threadIdx.x;   // 2*256*96 = 49152
  int dir = t / (256*96);
  int r = t % (256*96);
  int jj = r / 96, k = r % 96;
  const float* W = dir ? Wxb : Wxf;
  o[t] = (k < DIN_) ? (half_t)W[k*(4*UM_)+jj] : (half_t)0.f;
}

// ---- fill x cols [0..16) = word emb, [48..68) = pos, [68..76) = par
__global__ void k_xfill(const int* __restrict__ word_in, const float* __restrict__ emb_wor,
                        const float* __restrict__ pos, const float* __restrict__ par,
                        float* __restrict__ x){
  int r = blockIdx.x*4 + threadIdx.x/80;
  int c = threadIdx.x%80;
  float v;
  if (c < DW_)                     v = emb_wor[word_in[r]*DW_ + c];
  else if (c < DW_+UC_)            return;             // char kernel fills
  else if (c < DW_+UC_+POS_)       v = pos[r*POS_ + (c-(DW_+UC_))];
  else if (c < DIN_)               v = par[r*PAR_ + (c-(DW_+UC_+POS_))];
  else                             return;             // pad, never read
  x[r*XS_ + c] = v;
}

// ---- char LSTM: wave = 1 seq; lane u&31 = unit, lane>>5 = gate-half.
// half0: gates i,f; half1: g,o. 32 packed-f16 weight uints/thread, dot2 math.
// All exchange wave-local LDS: zero barriers in the 20-step loop.
__global__ __launch_bounds__(512,4) void k_char(const int* __restrict__ char_in,
        const float* __restrict__ xzc, const half_t* __restrict__ chT,
        float* __restrict__ x){
  __shared__ unsigned int hbuf2[8][16];   // h as h2 pairs, per wave
  __shared__ float2 zex[8][64];
  __shared__ int sidx[8*TC_];
  const int tid = threadIdx.x;
  const int w8 = tid >> 6;              // wave = seq slot 0..7
  const int lane = tid & 63;
  const int u = lane & 31;
  const int half = lane >> 5;
  const int seq = blockIdx.x*8 + w8;

  if (tid < 8*TC_) sidx[tid] = char_in[blockIdx.x*(8*TC_) + tid];
  if (half==0 && u<16) hbuf2[w8][u] = 0;

  // cols: a = half*64+u, b = half*64+32+u; chT[col*32+k] -> 16 uints each
  unsigned int wa[16], wb[16];
  {
    const uint4* pa = reinterpret_cast<const uint4*>(chT + (half*64+u)*32);
    const uint4* pb = reinterpret_cast<const uint4*>(chT + (half*64+32+u)*32);
    #pragma unroll
    for (int q=0;q<4;q++){
      uint4 va = pa[q], vb = pb[q];
      wa[q*4+0]=va.x; wa[q*4+1]=va.y; wa[q*4+2]=va.z; wa[q*4+3]=va.w;
      wb[q*4+0]=vb.x; wb[q*4+1]=vb.y; wb[q*4+2]=vb.z; wb[q*4+3]=vb.w;
    }
  }
  #pragma unroll
  for (int k=0;k<16;k++){ asm volatile("" : "+v"(wa[k])); asm volatile("" : "+v"(wb[k])); }
  __syncthreads();

  float h = 0.f, c = 0.f;
  int idx = sidx[w8*TC_ + 0];
  float za0 = xzc[idx*(4*UC_) + half*64 + u];
  float zb0 = xzc[idx*(4*UC_) + half*64 + 32 + u];

  for (int t=0; t<TC_; t++){
    int idxn = (t+1 < TC_) ? sidx[w8*TC_ + t+1] : 0;
    float zan = xzc[idxn*(4*UC_) + half*64 + u];        // prefetch
    float zbn = xzc[idxn*(4*UC_) + half*64 + 32 + u];

    float za = za0, zb = zb0;
    const uint4* hb = reinterpret_cast<const uint4*>(&hbuf2[w8][0]); // broadcast
    uint4 q0=hb[0], q1=hb[1], q2=hb[2], q3=hb[3];
    unsigned int hu[16] = {q0.x,q0.y,q0.z,q0.w, q1.x,q1.y,q1.z,q1.w,
                           q2.x,q2.y,q2.z,q2.w, q3.x,q3.y,q3.z,q3.w};
    #pragma unroll
    for (int k=0;k<16;k++){
      za = dot2u(wa[k], hu[k], za);
      zb = dot2u(wb[k], hu[k], zb);
    }
    zex[w8][lane] = make_float2(za, zb);  // half1 publishes (zg,zo)
    if (half == 0){
      float2 p = zex[w8][32+u];           // same wave, in-order DS
      float zi = za, zf = zb, zg = p.x, zo = p.y;
      float cn = fast_sig(zf)*c + fast_sig(zi)*fast_tanh(zg);
      float hn = fast_sig(zo)*fast_tanh(cn);
      bool m = (idx != 0);
      c = m ? cn : c;
      h = m ? hn : h;
      reinterpret_cast<half_t*>(&hbuf2[w8][0])[u] = (half_t)h;  // b16 write
    }
    idx = idxn; za0 = zan; zb0 = zbn;
  }
  if (half == 0) x[seq*XS_ + DW_ + u] = h;
}

// ---- xz GEMM via dot2: x staged as packed f16 in LDS (broadcast reads),
// 40 weight uints/thread. Output [row][dir][u*4+g] f16.
__global__ __launch_bounds__(512,1) void k_xz(const float* __restrict__ x,
      const half_t* __restrict__ wxT_h,
      const float* __restrict__ b_f, const float* __restrict__ b_b,
      half_t* __restrict__ xz){
  __shared__ unsigned int xs[16][40];     // 16 rows x 80 halves (76+pad)
  const int j = threadIdx.x;
  const int jj = j & 255;
  const bool bwd = (j >= 256);
  const float bj = bwd ? b_b[jj] : b_f[jj];
  const int u = jj & 63, g = jj >> 6;
  const int ocol = (bwd ? 256 : 0) + u*4 + g;

  unsigned int wq[40];
  {
    const uint4* p = reinterpret_cast<const uint4*>(wxT_h + (size_t)((bwd?256:0)+jj)*96);
    #pragma unroll
    for (int q=0;q<10;q++){
      uint4 v = p[q];
      wq[q*4+0]=v.x; wq[q*4+1]=v.y; wq[q*4+2]=v.z; wq[q*4+3]=v.w;
    }
  }
  #pragma unroll
  for (int k=0;k<40;k++) asm volatile("" : "+v"(wq[k]));

  const int rowbase = blockIdx.x*16;
  for (int i=j; i<16*40; i+=512){
    int r = i/40, q = i%40;
    unsigned int pk = 0;
    if (q < 38){
      float v0 = x[(size_t)(rowbase+r)*XS_ + 2*q];
      float v1 = x[(size_t)(rowbase+r)*XS_ + 2*q+1];
      union{h2 h; unsigned int u;} cv; cv.h = h2{(half_t)v0,(half_t)v1};
      pk = cv.u;
    }
    xs[r][q] = pk;
  }
  __syncthreads();

  for (int r=0; r<16; r++){
    const uint4* xr = reinterpret_cast<const uint4*>(&xs[r][0]);  // broadcast
    float acc = bj;
    #pragma unroll
    for (int q=0;q<10;q++){
      uint4 v = xr[q];
      acc = dot2u(wq[q*4+0], v.x, acc);
      acc = dot2u(wq[q*4+1], v.y, acc);
      acc = dot2u(wq[q*4+2], v.z, acc);
      acc = dot2u(wq[q*4+3], v.w, acc);
    }
    xz[(size_t)(rowbase+r)*512 + ocol] = (half_t)acc;
  }
}

// ---- word LSTM: block = (batch,dir), 4 waves. Thread (w,l): cols {m*64+l},
// k-slice [w*16,w*16+16) as 8 packed uints -> 32 dot2/step. zpart transposed
// [col][4] (xor-swizzled slot) -> 4x b128 + 12 adds. One raw barrier/step.
__global__ __launch_bounds__(256,1) void k_rnn(const half_t* __restrict__ xz,
      const int* __restrict__ word_in, const half_t* __restrict__ whT_h,
      float* __restrict__ hcat){
  __shared__ float zpart[2][4*UM_][4];
  __shared__ unsigned int hbuf2[4][32];   // h as h2 pairs, per wave
  __shared__ int wm[T_];
  const int j = threadIdx.x;
  const int w = j >> 6;
  const int l = j & 63;
  const int dir = blockIdx.x & 1;
  const int b = blockIdx.x >> 1;
  const int sw = (l >> 3) & 3;            // slot swizzle (bank spread)

  unsigned int wt[4][8];
  {
    const half_t* wbase = whT_h + (size_t)dir*256*64;
    #pragma unroll
    for (int m=0;m<4;m++){
      const uint4* p = reinterpret_cast<const uint4*>(wbase + (m*64+l)*64 + w*16);
      uint4 q0 = p[0], q1 = p[1];
      wt[m][0]=q0.x; wt[m][1]=q0.y; wt[m][2]=q0.z; wt[m][3]=q0.w;
      wt[m][4]=q1.x; wt[m][5]=q1.y; wt[m][6]=q1.z; wt[m][7]=q1.w;
    }
  }
  #pragma unroll
  for (int m=0;m<4;m++)
    #pragma unroll
    for (int k=0;k<8;k++)
      asm volatile("" : "+v"(wt[m][k]));

  for (int t=j; t<T_; t+=256) wm[t] = word_in[b*T_ + (dir ? (T_-1-t) : t)];
  if (l < 32) hbuf2[w][l] = 0;
  __syncthreads();

  float h = 0.f, cc = 0.f;
  int row0 = b*T_ + (dir ? T_-1 : 0);
  const half_t* xp = xz + (size_t)row0*512 + dir*256 + l*4;
  const ptrdiff_t dstep = dir ? -512 : 512;
  float* hout = hcat + (size_t)row0*(2*UM_) + dir*UM_ + l;
  const ptrdiff_t hstep = dir ? -(2*UM_) : (2*UM_);

  ushort4 zxu = *reinterpret_cast<const ushort4*>(xp);

  for (int t=0; t<T_; t++){
    ushort4 zxn = {0,0,0,0};
    if (t+1 < T_) zxn = *reinterpret_cast<const ushort4*>(xp + dstep); // prefetch

    // h slice: 8 uints (broadcast within wave)
    const uint4* hb = reinterpret_cast<const uint4*>(&hbuf2[w][w*8]);
    uint4 q0 = hb[0], q1 = hb[1];
    unsigned int hu[8] = {q0.x,q0.y,q0.z,q0.w, q1.x,q1.y,q1.z,q1.w};
    #pragma unroll
    for (int m=0;m<4;m++){
      float a = 0.f;
      #pragma unroll
      for (int k=0;k<8;k++) a = dot2u(wt[m][k], hu[k], a);
      zpart[t&1][m*64+l][w ^ sw] = a;
    }
    asm volatile("s_waitcnt lgkmcnt(0)" ::: "memory");
    __builtin_amdgcn_s_barrier();
    asm volatile("" ::: "memory");

    float4 s0 = *reinterpret_cast<const float4*>(&zpart[t&1][      l][0]);
    float4 s1 = *reinterpret_cast<const float4*>(&zpart[t&1][ 64 + l][0]);
    float4 s2 = *reinterpret_cast<const float4*>(&zpart[t&1][128 + l][0]);
    float4 s3 = *reinterpret_cast<const float4*>(&zpart[t&1][192 + l][0]);
    float zi = us2f(zxu.x) + ((s0.x+s0.y)+(s0.z+s0.w));
    float zf = us2f(zxu.y) + ((s1.x+s1.y)+(s1.z+s1.w));
    float zg = us2f(zxu.z) + ((s2.x+s2.y)+(s2.z+s2.w));
    float zo = us2f(zxu.w) + ((s3.x+s3.y)+(s3.z+s3.w));
    int mw = wm[t];
    float cn = fast_sig(zf)*cc + fast_sig(zi)*fast_tanh(zg);
    float hn = fast_sig(zo)*fast_tanh(cn);
    if (mw != 0){ cc = cn; h = hn; }      // all waves update redundantly
    reinterpret_cast<half_t*>(&hbuf2[w][0])[l] = (half_t)h;  // own-wave copy
    if (w == 0) *hout = h;                // fire-and-forget store
    hout += hstep;
    zxu = zxn; xp += dstep;
  }
}

// ---- dense + softmax
__global__ void k_dense(const float* __restrict__ hcat, const float* __restrict__ W,
                        const float* __restrict__ bias, float* __restrict__ out){
  int r = blockIdx.x*256 + threadIdx.x;
  const float4* h4 = reinterpret_cast<const float4*>(hcat + (size_t)r*(2*UM_));
  float a0=bias[0], a1=bias[1], a2=bias[2], a3=bias[3];
  #pragma unroll
  for (int k4=0;k4<32;k4++){
    float4 hv = h4[k4];
    float he[4] = {hv.x, hv.y, hv.z, hv.w};
    #pragma unroll
    for (int e=0;e<4;e++){
      int k = k4*4+e;
      a0 += he[e]*W[k*4+0]; a1 += he[e]*W[k*4+1];
      a2 += he[e]*W[k*4+2]; a3 += he[e]*W[k*4+3];
    }
  }
  float mx = fmaxf(fmaxf(a0,a1), fmaxf(a2,a3));
  float e0=__expf(a0-mx), e1=__expf(a1-mx), e2=__expf(a2-mx), e3=__expf(a3-mx);
  float s = __builtin_amdgcn_rcpf(e0+e1+e2+e3);
  out[r*4+0]=e0*s; out[r*4+1]=e1*s; out[r*4+2]=e2*s; out[r*4+3]=e3*s;
}

extern "C" void kernel_launch(void* const* d_in, const int* in_sizes, int n_in,
                              void* d_out, int out_size, void* d_ws, size_t ws_size,
                              hipStream_t stream) {
  const int*   word_in  = (const int*)  d_in[0];
  const int*   char_in  = (const int*)  d_in[1];
  const float* inp_pos  = (const float*)d_in[2];
  const float* inp_par  = (const float*)d_in[3];
  const float* emb_wor  = (const float*)d_in[4];
  const float* emb_char = (const float*)d_in[5];
  const float* char_Wx  = (const float*)d_in[6];
  const float* char_Wh  = (const float*)d_in[7];
  const float* char_b   = (const float*)d_in[8];
  const float* fwd_Wx   = (const float*)d_in[9];
  const float* fwd_Wh   = (const float*)d_in[10];
  const float* fwd_b    = (const float*)d_in[11];
  const float* bwd_Wx   = (const float*)d_in[12];
  const float* bwd_Wh   = (const float*)d_in[13];
  const float* bwd_b    = (const float*)d_in[14];
  const float* dense_W  = (const float*)d_in[15];
  const float* dense_b  = (const float*)d_in[16];
  float* out = (float*)d_out;

  float* xw   = (float*)d_ws;                      // NROW*80  f32
  float* hcat = xw + (size_t)NROW*XS_;             // NROW*128 f32
  float* xzc  = hcat + (size_t)NROW*128;           // 132*128  f32
  float* fp   = xzc + (size_t)VC_*128;
  half_t* chT   = (half_t*)fp;                     // 128*32  f16
  half_t* whT_h = chT + 128*32;                    // 2*256*64 f16
  half_t* wxT_h = whT_h + 2*256*64;                // 2*256*96 f16
  half_t* xzw   = wxT_h + 2*256*96;                // NROW*512 f16

  k_xzc  <<<VC_, 4*UC_, 0, stream>>>(emb_char, char_Wx, char_b, xzc);
  k_chT  <<<16, 256, 0, stream>>>(char_Wh, chT);
  k_whT  <<<128, 256, 0, stream>>>(fwd_Wh, bwd_Wh, whT_h);
  k_wxT  <<<192, 256, 0, stream>>>(fwd_Wx, bwd_Wx, wxT_h);
  k_xfill<<<NROW/4, 320, 0, stream>>>(word_in, emb_wor, inp_pos, inp_par, xw);
  k_char <<<NROW/8, 512, 0, stream>>>(char_in, xzc, chT, xw);
  k_xz   <<<NROW/16, 512, 0, stream>>>(xw, wxT_h, fwd_b, bwd_b, xzw);
  k_rnn  <<<2*B_, 256, 0, stream>>>(xzw, word_in, whT_h, hcat);
  k_dense<<<NROW/256, 256, 0, stream>>>(hcat, dense_W, dense_b, out);
}